// Round 6
// baseline (423.951 us; speedup 1.0000x reference)
//
#include <hip/hip_runtime.h>

typedef __bf16 bfrag __attribute__((ext_vector_type(8)));
typedef float f32x4 __attribute__((ext_vector_type(4)));

__device__ __forceinline__ unsigned short f2bf(float f) {
    unsigned int u = __float_as_uint(f);
    unsigned int r = (u + 0x7fffu + ((u >> 16) & 1u)) >> 16;
    return (unsigned short)r;
}
__device__ __forceinline__ float bf2f(unsigned short h) {
    return __uint_as_float(((unsigned int)h) << 16);
}

__device__ __forceinline__ void gll16(const unsigned short* g, unsigned short* l) {
    __builtin_amdgcn_global_load_lds(
        (const __attribute__((address_space(1))) unsigned int*)g,
        (__attribute__((address_space(3))) unsigned int*)l, 16, 0, 0);
}

// Swizzled frag address (shorts): logical (row r, 16B-k-chunk kc) of a BK=64 tile.
// Wave-chunk = 8 rows x 8 chunks (1KB); slot within = (r&7)*8 + (kc ^ (r&7)).
__device__ __forceinline__ int swz(int r, int kc) {
    return (r >> 3) * 512 + (((r & 7) * 8 + (kc ^ (r & 7))) * 8);
}

// ---------------- generic NT GEMM, BK=64, swizzled LDS ----------------
// C = A[M,K] * B^T, B is [N,K]. z-batched via element strides. blockIdx.x = n!
// EPI: 0 = store bf16 (v*scale); 1 = sigmoid -> bf16; 2 = +bias[col]+residual -> bf16
template<int BM, int BN, int WR, int WC, int EPI>
__global__ __launch_bounds__(256) void gemm_nt(
    const unsigned short* __restrict__ A, const unsigned short* __restrict__ B,
    unsigned short* __restrict__ Cb,
    const unsigned short* __restrict__ R, const float* __restrict__ bias,
    int M, int N, int K, float scale,
    size_t sAz, size_t sBz, size_t sCz)
{
    constexpr int BK = 64;
    constexpr int WTM = BM / (WR * 16);
    constexpr int WTN = BN / (WC * 16);
    __shared__ unsigned short sA[BM * BK];
    __shared__ unsigned short sB[BN * BK];

    A += blockIdx.z * sAz;
    B += blockIdx.z * sBz;

    const int tid  = threadIdx.x;
    const int w    = tid >> 6;
    const int lane = tid & 63;
    const int wm = w / WC;
    const int wn = w % WC;
    const int bn0 = blockIdx.x * BN;      // n-fastest for L2 stripe reuse
    const int bm0 = blockIdx.y * BM;
    const int rl  = lane >> 3;            // row within wave-chunk (0..7)
    const int kcs = (lane & 7) ^ rl;      // swizzled source k-chunk
    const int mrow = lane & 15;
    const int kgrp = lane >> 4;

    f32x4 acc[WTM][WTN] = {};

    for (int k0 = 0; k0 < K; k0 += BK) {
        #pragma unroll
        for (int i = 0; i < BM / 32; ++i) {
            int wc = w * (BM / 32) + i;
            gll16(A + (size_t)(bm0 + wc * 8 + rl) * K + k0 + kcs * 8,
                  &sA[wc * 512 + lane * 8]);
        }
        #pragma unroll
        for (int i = 0; i < BN / 32; ++i) {
            int wc = w * (BN / 32) + i;
            gll16(B + (size_t)(bn0 + wc * 8 + rl) * K + k0 + kcs * 8,
                  &sB[wc * 512 + lane * 8]);
        }
        __syncthreads();

        #pragma unroll
        for (int kh = 0; kh < 2; ++kh) {
            bfrag af[WTM], bfr[WTN];
            #pragma unroll
            for (int mt = 0; mt < WTM; ++mt)
                af[mt] = *(const bfrag*)&sA[swz(wm * WTM * 16 + mt * 16 + mrow, kh * 4 + kgrp)];
            #pragma unroll
            for (int nt = 0; nt < WTN; ++nt)
                bfr[nt] = *(const bfrag*)&sB[swz(wn * WTN * 16 + nt * 16 + mrow, kh * 4 + kgrp)];
            #pragma unroll
            for (int mt = 0; mt < WTM; ++mt)
                #pragma unroll
                for (int nt = 0; nt < WTN; ++nt)
                    acc[mt][nt] = __builtin_amdgcn_mfma_f32_16x16x32_bf16(af[mt], bfr[nt], acc[mt][nt], 0, 0, 0);
        }
        __syncthreads();
    }

    #pragma unroll
    for (int mt = 0; mt < WTM; ++mt) {
        #pragma unroll
        for (int nt = 0; nt < WTN; ++nt) {
            int grow0 = bm0 + wm * WTM * 16 + mt * 16 + kgrp * 4;
            int gcol  = bn0 + wn * WTN * 16 + nt * 16 + mrow;
            #pragma unroll
            for (int r = 0; r < 4; ++r) {
                float v = acc[mt][nt][r];
                size_t off = blockIdx.z * sCz + (size_t)(grow0 + r) * N + gcol;
                if (EPI == 0) {
                    Cb[off] = f2bf(v * scale);
                } else if (EPI == 1) {
                    Cb[off] = f2bf(1.0f / (1.0f + __expf(-v)));
                } else {
                    Cb[off] = f2bf(v + bias[gcol] + bf2f(R[off]));
                }
            }
        }
    }
}

// ---------------- fused QKV projection (BK=64, swizzled) ----------------
// z=0: q = (yn Wq^T)*SCALE ; z=1: k = xn Wk^T ; z=2: vt-pack of xn Wv^T
__global__ __launch_bounds__(256) void qkv_proj(
    const unsigned short* __restrict__ xn, const unsigned short* __restrict__ yn,
    const unsigned short* __restrict__ W,   // [3][576][576] bf16
    unsigned short* __restrict__ qk,        // q then k, [2][16384][576]
    unsigned short* __restrict__ vt,        // [8][576][2048]
    float scale)
{
    constexpr int BM = 128, BN = 64, BK = 64;
    constexpr int WTM = 4, WTN = 2;         // WR=2, WC=2
    __shared__ unsigned short sA[BM * BK];
    __shared__ unsigned short sB[BN * BK];

    const int z = blockIdx.z;
    const unsigned short* A = (z == 0) ? yn : xn;
    const unsigned short* B = W + (size_t)z * 576 * 576;
    const float sc = (z == 0) ? scale : 1.0f;

    const int tid  = threadIdx.x;
    const int w    = tid >> 6;
    const int lane = tid & 63;
    const int wm = w >> 1;
    const int wn = w & 1;
    const int bn0 = blockIdx.x * BN;
    const int bm0 = blockIdx.y * BM;
    const int rl  = lane >> 3;
    const int kcs = (lane & 7) ^ rl;
    const int mrow = lane & 15;
    const int kgrp = lane >> 4;

    f32x4 acc[WTM][WTN] = {};

    for (int k0 = 0; k0 < 576; k0 += BK) {
        #pragma unroll
        for (int i = 0; i < BM / 32; ++i) {
            int wc = w * (BM / 32) + i;
            gll16(A + (size_t)(bm0 + wc * 8 + rl) * 576 + k0 + kcs * 8,
                  &sA[wc * 512 + lane * 8]);
        }
        #pragma unroll
        for (int i = 0; i < BN / 32; ++i) {
            int wc = w * (BN / 32) + i;
            gll16(B + (size_t)(bn0 + wc * 8 + rl) * 576 + k0 + kcs * 8,
                  &sB[wc * 512 + lane * 8]);
        }
        __syncthreads();

        #pragma unroll
        for (int kh = 0; kh < 2; ++kh) {
            bfrag af[WTM], bfr[WTN];
            #pragma unroll
            for (int mt = 0; mt < WTM; ++mt)
                af[mt] = *(const bfrag*)&sA[swz(wm * WTM * 16 + mt * 16 + mrow, kh * 4 + kgrp)];
            #pragma unroll
            for (int nt = 0; nt < WTN; ++nt)
                bfr[nt] = *(const bfrag*)&sB[swz(wn * WTN * 16 + nt * 16 + mrow, kh * 4 + kgrp)];
            #pragma unroll
            for (int mt = 0; mt < WTM; ++mt)
                #pragma unroll
                for (int nt = 0; nt < WTN; ++nt)
                    acc[mt][nt] = __builtin_amdgcn_mfma_f32_16x16x32_bf16(af[mt], bfr[nt], acc[mt][nt], 0, 0, 0);
        }
        __syncthreads();
    }

    #pragma unroll
    for (int mt = 0; mt < WTM; ++mt) {
        #pragma unroll
        for (int nt = 0; nt < WTN; ++nt) {
            int grow0 = bm0 + wm * WTM * 16 + mt * 16 + kgrp * 4;
            int gcol  = bn0 + wn * WTN * 16 + nt * 16 + mrow;
            if (z == 2) {
                ushort4 o;
                o.x = f2bf(acc[mt][nt][0]);
                o.y = f2bf(acc[mt][nt][1]);
                o.z = f2bf(acc[mt][nt][2]);
                o.w = f2bf(acc[mt][nt][3]);
                size_t dst = (((size_t)(grow0 >> 11) * 576 + gcol) << 11) + (grow0 & 2047);
                *(ushort4*)(vt + dst) = o;
            } else {
                unsigned short* C = qk + (size_t)z * 16384 * 576;
                #pragma unroll
                for (int r = 0; r < 4; ++r)
                    C[(size_t)(grow0 + r) * 576 + gcol] = f2bf(acc[mt][nt][r] * sc);
            }
        }
    }
}

// ---------------- LayerNorms ----------------
__global__ __launch_bounds__(256) void ln_pair(
    const float* __restrict__ x, const float* __restrict__ gx, const float* __restrict__ bx,
    unsigned short* __restrict__ xn,
    const float* __restrict__ y, const float* __restrict__ gy, const float* __restrict__ by,
    unsigned short* __restrict__ yn)
{
    const float* src = blockIdx.y ? y : x;
    const float* g   = blockIdx.y ? gy : gx;
    const float* bb  = blockIdx.y ? by : bx;
    unsigned short* o = blockIdx.y ? yn : xn;

    const int row  = blockIdx.x * 4 + (threadIdx.x >> 6);
    const int lane = threadIdx.x & 63;
    const float* xr = src + (size_t)row * 576;
    float vals[9];
    float s = 0.f, ss = 0.f;
    #pragma unroll
    for (int i = 0; i < 9; ++i) {
        float v = xr[lane + i * 64];
        vals[i] = v; s += v; ss += v * v;
    }
    #pragma unroll
    for (int off = 32; off > 0; off >>= 1) {
        s  += __shfl_xor(s, off, 64);
        ss += __shfl_xor(ss, off, 64);
    }
    float mean = s * (1.0f / 576.0f);
    float var  = ss * (1.0f / 576.0f) - mean * mean;
    float rstd = rsqrtf(var + 1e-5f);
    #pragma unroll
    for (int i = 0; i < 9; ++i) {
        int c = lane + i * 64;
        o[(size_t)row * 576 + c] = f2bf((vals[i] - mean) * rstd * g[c] + bb[c]);
    }
}

// Final LN: bf16 in -> fp32 out
__global__ __launch_bounds__(256) void ln_final(
    const unsigned short* __restrict__ x, const float* __restrict__ g,
    const float* __restrict__ bb, float* __restrict__ outp)
{
    const int row  = blockIdx.x * 4 + (threadIdx.x >> 6);
    const int lane = threadIdx.x & 63;
    const unsigned short* xr = x + (size_t)row * 576;
    float vals[9];
    float s = 0.f, ss = 0.f;
    #pragma unroll
    for (int i = 0; i < 9; ++i) {
        float v = bf2f(xr[lane + i * 64]);
        vals[i] = v; s += v; ss += v * v;
    }
    #pragma unroll
    for (int off = 32; off > 0; off >>= 1) {
        s  += __shfl_xor(s, off, 64);
        ss += __shfl_xor(ss, off, 64);
    }
    float mean = s * (1.0f / 576.0f);
    float var  = ss * (1.0f / 576.0f) - mean * mean;
    float rstd = rsqrtf(var + 1e-5f);
    #pragma unroll
    for (int i = 0; i < 9; ++i) {
        int c = lane + i * 64;
        outp[(size_t)row * 576 + c] = (vals[i] - mean) * rstd * g[c] + bb[c];
    }
}

__global__ __launch_bounds__(256) void cvt4w(
    const float* __restrict__ s0, const float* __restrict__ s1,
    const float* __restrict__ s2, const float* __restrict__ s3,
    unsigned short* __restrict__ dst)
{
    const float* srcs[4] = {s0, s1, s2, s3};
    const float* src = srcs[blockIdx.y];
    unsigned short* d = dst + (size_t)blockIdx.y * 576 * 576;
    int i = (blockIdx.x * 256 + threadIdx.x) * 4;
    float4 f = *(const float4*)(src + i);
    ushort4 o;
    o.x = f2bf(f.x); o.y = f2bf(f.y); o.z = f2bf(f.z); o.w = f2bf(f.w);
    *(ushort4*)(d + i) = o;
}

extern "C" void kernel_launch(void* const* d_in, const int* in_sizes, int n_in,
                              void* d_out, int out_size, void* d_ws, size_t ws_size,
                              hipStream_t stream)
{
    const float* x  = (const float*)d_in[0];
    const float* y  = (const float*)d_in[1];
    const float* Wq = (const float*)d_in[2];
    const float* Wk = (const float*)d_in[3];
    const float* Wv = (const float*)d_in[4];
    const float* Wp = (const float*)d_in[5];
    const float* bp = (const float*)d_in[6];
    const float* gx = (const float*)d_in[7];
    const float* bx = (const float*)d_in[8];
    const float* gy = (const float*)d_in[9];
    const float* by = (const float*)d_in[10];
    const float* gz = (const float*)d_in[11];
    const float* bz = (const float*)d_in[12];

    constexpr size_t WB = 576 * 576 * 2;           // one bf16 weight matrix (bytes)
    constexpr size_t XB = 16384ull * 576 * 2;      // one bf16 activation (bytes)
    constexpr size_t TOK = (size_t)2048 * 576;     // elements per batch of activation
    constexpr size_t SB  = (size_t)2048 * 2048;    // elements per batch of S

    char* w = (char*)d_ws;
    unsigned short* wq = (unsigned short*)(w);          // wq,wk,wv,wp contiguous
    unsigned short* wp = (unsigned short*)(w + 3 * WB);
    unsigned short* xn = (unsigned short*)(w + 4 * WB);
    unsigned short* yn = (unsigned short*)(w + 4 * WB + XB);
    unsigned short* q  = (unsigned short*)(w + 4 * WB + 2 * XB);
    unsigned short* k  = (unsigned short*)(w + 4 * WB + 3 * XB);
    unsigned short* vt = (unsigned short*)(w + 4 * WB + 4 * XB);  // [8][576][2048]
    unsigned short* S  = (unsigned short*)(w + 4 * WB + 5 * XB);  // [8][2048][2048], 67 MB
    unsigned short* attno = yn;       // yn dead after q projection
    unsigned short* T = q;            // q dead after attention; bf16 T

    cvt4w<<<dim3(324, 4), 256, 0, stream>>>(Wq, Wk, Wv, Wp, wq);

    ln_pair<<<dim3(4096, 2), 256, 0, stream>>>(x, gx, bx, xn, y, gy, by, yn);

    const float SCALE = 0.041666666666666664f;  // 576^-0.5 = 1/24, folded into q
    // q/k/v projections, one launch; grid.x = n-tiles (9), grid.y = m-tiles (128)
    qkv_proj<<<dim3(9, 128, 3), 256, 0, stream>>>(xn, yn, wq, q, vt, SCALE);

    // S_b = sigmoid(q_b k_b^T)  [2048 x 2048] x 8
    gemm_nt<128, 128, 2, 2, 1><<<dim3(16, 16, 8), 256, 0, stream>>>(
        q, k, S, nullptr, nullptr, 2048, 2048, 576, 1.0f, TOK, TOK, SB);
    // O_b = S_b v_b  (NT vs Vt)  [2048 x 576] x 8
    gemm_nt<128, 64, 2, 2, 0><<<dim3(9, 16, 8), 256, 0, stream>>>(
        S, vt, attno, nullptr, nullptr, 2048, 576, 2048, 1.0f, SB, TOK, TOK);

    // T = attno Wp^T + bp + xn  (bf16)
    gemm_nt<128, 64, 2, 2, 2><<<dim3(9, 128, 1), 256, 0, stream>>>(
        attno, wp, T, xn, bp, 16384, 576, 576, 1.0f, 0, 0, 0);
    // out = LN(T)
    ln_final<<<4096, 256, 0, stream>>>(T, gz, bz, (float*)d_out);
}

// Round 7
// 325.297 us; speedup vs baseline: 1.3033x; 1.3033x over previous
//
#include <hip/hip_runtime.h>

typedef __bf16 bfrag __attribute__((ext_vector_type(8)));
typedef float f32x4 __attribute__((ext_vector_type(4)));

__device__ __forceinline__ unsigned short f2bf(float f) {
    unsigned int u = __float_as_uint(f);
    unsigned int r = (u + 0x7fffu + ((u >> 16) & 1u)) >> 16;
    return (unsigned short)r;
}
__device__ __forceinline__ float bf2f(unsigned short h) {
    return __uint_as_float(((unsigned int)h) << 16);
}

__device__ __forceinline__ void gll16(const unsigned short* g, unsigned short* l) {
    __builtin_amdgcn_global_load_lds(
        (const __attribute__((address_space(1))) unsigned int*)g,
        (__attribute__((address_space(3))) unsigned int*)l, 16, 0, 0);
}

// Swizzled frag address (shorts): logical (row r, 16B-k-chunk kc) of a BK=64 tile.
// Wave-chunk = 8 rows x 8 chunks (1KB); slot = (r&7)*8 + (kc ^ (r&7)). Conflict-free.
__device__ __forceinline__ int swz(int r, int kc) {
    return (r >> 3) * 512 + (((r & 7) * 8 + (kc ^ (r & 7))) * 8);
}

// ---------------- generic NT GEMM, BK=64, swizzled LDS, XCD-aware 1D grid ----------------
// C = A[M,K] * B^T, B is [N,K]. 1D grid; decode: xcd=id&7 gets whole (z,m)-stripes so
// the A-stripe is fetched once into that XCD's L2 and reused by all TN n-blocks.
// EPI: 0 = store bf16 (v*scale); 1 = sigmoid -> bf16; 2 = +bias[col]+residual -> bf16
template<int BM, int BN, int WR, int WC, int EPI>
__global__ __launch_bounds__(256) void gemm_nt(
    const unsigned short* __restrict__ A, const unsigned short* __restrict__ B,
    unsigned short* __restrict__ Cb,
    const unsigned short* __restrict__ R, const float* __restrict__ bias,
    int N, int K, int TM, int TN, float scale,
    size_t sAz, size_t sBz, size_t sCz)
{
    constexpr int BK = 64;
    constexpr int WTM = BM / (WR * 16);
    constexpr int WTN = BN / (WC * 16);
    __shared__ unsigned short sA[BM * BK];
    __shared__ unsigned short sB[BN * BK];

    // XCD-aware decode
    const int id  = blockIdx.x;
    const int j   = id >> 3;
    const int s   = (id & 7) + 8 * (j / TN);
    const int bn0 = (j % TN) * BN;
    const int bm0 = (s % TM) * BM;
    const int z   = s / TM;

    A += (size_t)z * sAz;
    B += (size_t)z * sBz;

    const int tid  = threadIdx.x;
    const int w    = tid >> 6;
    const int lane = tid & 63;
    const int wm = w / WC;
    const int wn = w % WC;
    const int rl  = lane >> 3;            // row within wave-chunk (0..7)
    const int kcs = (lane & 7) ^ rl;      // swizzled source k-chunk
    const int mrow = lane & 15;
    const int kgrp = lane >> 4;

    f32x4 acc[WTM][WTN] = {};

    for (int k0 = 0; k0 < K; k0 += BK) {
        #pragma unroll
        for (int i = 0; i < BM / 32; ++i) {
            int wc = w * (BM / 32) + i;
            gll16(A + (size_t)(bm0 + wc * 8 + rl) * K + k0 + kcs * 8,
                  &sA[wc * 512 + lane * 8]);
        }
        #pragma unroll
        for (int i = 0; i < BN / 32; ++i) {
            int wc = w * (BN / 32) + i;
            gll16(B + (size_t)(bn0 + wc * 8 + rl) * K + k0 + kcs * 8,
                  &sB[wc * 512 + lane * 8]);
        }
        __syncthreads();

        #pragma unroll
        for (int kh = 0; kh < 2; ++kh) {
            bfrag af[WTM], bfr[WTN];
            #pragma unroll
            for (int mt = 0; mt < WTM; ++mt)
                af[mt] = *(const bfrag*)&sA[swz(wm * WTM * 16 + mt * 16 + mrow, kh * 4 + kgrp)];
            #pragma unroll
            for (int nt = 0; nt < WTN; ++nt)
                bfr[nt] = *(const bfrag*)&sB[swz(wn * WTN * 16 + nt * 16 + mrow, kh * 4 + kgrp)];
            #pragma unroll
            for (int mt = 0; mt < WTM; ++mt)
                #pragma unroll
                for (int nt = 0; nt < WTN; ++nt)
                    acc[mt][nt] = __builtin_amdgcn_mfma_f32_16x16x32_bf16(af[mt], bfr[nt], acc[mt][nt], 0, 0, 0);
        }
        __syncthreads();
    }

    #pragma unroll
    for (int mt = 0; mt < WTM; ++mt) {
        #pragma unroll
        for (int nt = 0; nt < WTN; ++nt) {
            int grow0 = bm0 + wm * WTM * 16 + mt * 16 + kgrp * 4;
            int gcol  = bn0 + wn * WTN * 16 + nt * 16 + mrow;
            #pragma unroll
            for (int r = 0; r < 4; ++r) {
                float v = acc[mt][nt][r];
                size_t off = (size_t)z * sCz + (size_t)(grow0 + r) * N + gcol;
                if (EPI == 0) {
                    Cb[off] = f2bf(v * scale);
                } else if (EPI == 1) {
                    Cb[off] = f2bf(1.0f / (1.0f + __expf(-v)));
                } else {
                    Cb[off] = f2bf(v + bias[gcol] + bf2f(R[off]));
                }
            }
        }
    }
}

// ---------------- fused QKV projection (BK=64, swizzled, XCD-aware) ----------------
// stripe decode gives z in [0,3): 0: q = (yn Wq^T)*SCALE; 1: k = xn Wk^T; 2: vt-pack of xn Wv^T
__global__ __launch_bounds__(256) void qkv_proj(
    const unsigned short* __restrict__ xn, const unsigned short* __restrict__ yn,
    const unsigned short* __restrict__ W,   // [3][576][576] bf16
    unsigned short* __restrict__ qk,        // q then k, [2][16384][576]
    unsigned short* __restrict__ vt,        // [8][576][2048]
    float scale)
{
    constexpr int BM = 128, BN = 64, BK = 64;
    constexpr int WTM = 4, WTN = 2;         // WR=2, WC=2
    __shared__ unsigned short sA[BM * BK];
    __shared__ unsigned short sB[BN * BK];

    const int id  = blockIdx.x;
    const int j   = id >> 3;
    const int s   = (id & 7) + 8 * (j / 9);   // TN = 9
    const int bn0 = (j % 9) * BN;
    const int bm0 = (s % 128) * BM;           // TM = 128
    const int z   = s / 128;

    const unsigned short* A = (z == 0) ? yn : xn;
    const unsigned short* B = W + (size_t)z * 576 * 576;
    const float sc = (z == 0) ? scale : 1.0f;

    const int tid  = threadIdx.x;
    const int w    = tid >> 6;
    const int lane = tid & 63;
    const int wm = w >> 1;
    const int wn = w & 1;
    const int rl  = lane >> 3;
    const int kcs = (lane & 7) ^ rl;
    const int mrow = lane & 15;
    const int kgrp = lane >> 4;

    f32x4 acc[WTM][WTN] = {};

    for (int k0 = 0; k0 < 576; k0 += BK) {
        #pragma unroll
        for (int i = 0; i < BM / 32; ++i) {
            int wc = w * (BM / 32) + i;
            gll16(A + (size_t)(bm0 + wc * 8 + rl) * 576 + k0 + kcs * 8,
                  &sA[wc * 512 + lane * 8]);
        }
        #pragma unroll
        for (int i = 0; i < BN / 32; ++i) {
            int wc = w * (BN / 32) + i;
            gll16(B + (size_t)(bn0 + wc * 8 + rl) * 576 + k0 + kcs * 8,
                  &sB[wc * 512 + lane * 8]);
        }
        __syncthreads();

        #pragma unroll
        for (int kh = 0; kh < 2; ++kh) {
            bfrag af[WTM], bfr[WTN];
            #pragma unroll
            for (int mt = 0; mt < WTM; ++mt)
                af[mt] = *(const bfrag*)&sA[swz(wm * WTM * 16 + mt * 16 + mrow, kh * 4 + kgrp)];
            #pragma unroll
            for (int nt = 0; nt < WTN; ++nt)
                bfr[nt] = *(const bfrag*)&sB[swz(wn * WTN * 16 + nt * 16 + mrow, kh * 4 + kgrp)];
            #pragma unroll
            for (int mt = 0; mt < WTM; ++mt)
                #pragma unroll
                for (int nt = 0; nt < WTN; ++nt)
                    acc[mt][nt] = __builtin_amdgcn_mfma_f32_16x16x32_bf16(af[mt], bfr[nt], acc[mt][nt], 0, 0, 0);
        }
        __syncthreads();
    }

    #pragma unroll
    for (int mt = 0; mt < WTM; ++mt) {
        #pragma unroll
        for (int nt = 0; nt < WTN; ++nt) {
            int grow0 = bm0 + wm * WTM * 16 + mt * 16 + kgrp * 4;
            int gcol  = bn0 + wn * WTN * 16 + nt * 16 + mrow;
            if (z == 2) {
                ushort4 o;
                o.x = f2bf(acc[mt][nt][0]);
                o.y = f2bf(acc[mt][nt][1]);
                o.z = f2bf(acc[mt][nt][2]);
                o.w = f2bf(acc[mt][nt][3]);
                size_t dst = (((size_t)(grow0 >> 11) * 576 + gcol) << 11) + (grow0 & 2047);
                *(ushort4*)(vt + dst) = o;
            } else {
                unsigned short* C = qk + (size_t)z * 16384 * 576;
                #pragma unroll
                for (int r = 0; r < 4; ++r)
                    C[(size_t)(grow0 + r) * 576 + gcol] = f2bf(acc[mt][nt][r] * sc);
            }
        }
    }
}

// ---------------- LayerNorms ----------------
__global__ __launch_bounds__(256) void ln_pair(
    const float* __restrict__ x, const float* __restrict__ gx, const float* __restrict__ bx,
    unsigned short* __restrict__ xn,
    const float* __restrict__ y, const float* __restrict__ gy, const float* __restrict__ by,
    unsigned short* __restrict__ yn)
{
    const float* src = blockIdx.y ? y : x;
    const float* g   = blockIdx.y ? gy : gx;
    const float* bb  = blockIdx.y ? by : bx;
    unsigned short* o = blockIdx.y ? yn : xn;

    const int row  = blockIdx.x * 4 + (threadIdx.x >> 6);
    const int lane = threadIdx.x & 63;
    const float* xr = src + (size_t)row * 576;
    float vals[9];
    float s = 0.f, ss = 0.f;
    #pragma unroll
    for (int i = 0; i < 9; ++i) {
        float v = xr[lane + i * 64];
        vals[i] = v; s += v; ss += v * v;
    }
    #pragma unroll
    for (int off = 32; off > 0; off >>= 1) {
        s  += __shfl_xor(s, off, 64);
        ss += __shfl_xor(ss, off, 64);
    }
    float mean = s * (1.0f / 576.0f);
    float var  = ss * (1.0f / 576.0f) - mean * mean;
    float rstd = rsqrtf(var + 1e-5f);
    #pragma unroll
    for (int i = 0; i < 9; ++i) {
        int c = lane + i * 64;
        o[(size_t)row * 576 + c] = f2bf((vals[i] - mean) * rstd * g[c] + bb[c]);
    }
}

// Final LN: bf16 in -> fp32 out
__global__ __launch_bounds__(256) void ln_final(
    const unsigned short* __restrict__ x, const float* __restrict__ g,
    const float* __restrict__ bb, float* __restrict__ outp)
{
    const int row  = blockIdx.x * 4 + (threadIdx.x >> 6);
    const int lane = threadIdx.x & 63;
    const unsigned short* xr = x + (size_t)row * 576;
    float vals[9];
    float s = 0.f, ss = 0.f;
    #pragma unroll
    for (int i = 0; i < 9; ++i) {
        float v = bf2f(xr[lane + i * 64]);
        vals[i] = v; s += v; ss += v * v;
    }
    #pragma unroll
    for (int off = 32; off > 0; off >>= 1) {
        s  += __shfl_xor(s, off, 64);
        ss += __shfl_xor(ss, off, 64);
    }
    float mean = s * (1.0f / 576.0f);
    float var  = ss * (1.0f / 576.0f) - mean * mean;
    float rstd = rsqrtf(var + 1e-5f);
    #pragma unroll
    for (int i = 0; i < 9; ++i) {
        int c = lane + i * 64;
        outp[(size_t)row * 576 + c] = (vals[i] - mean) * rstd * g[c] + bb[c];
    }
}

__global__ __launch_bounds__(256) void cvt4w(
    const float* __restrict__ s0, const float* __restrict__ s1,
    const float* __restrict__ s2, const float* __restrict__ s3,
    unsigned short* __restrict__ dst)
{
    const float* srcs[4] = {s0, s1, s2, s3};
    const float* src = srcs[blockIdx.y];
    unsigned short* d = dst + (size_t)blockIdx.y * 576 * 576;
    int i = (blockIdx.x * 256 + threadIdx.x) * 4;
    float4 f = *(const float4*)(src + i);
    ushort4 o;
    o.x = f2bf(f.x); o.y = f2bf(f.y); o.z = f2bf(f.z); o.w = f2bf(f.w);
    *(ushort4*)(d + i) = o;
}

extern "C" void kernel_launch(void* const* d_in, const int* in_sizes, int n_in,
                              void* d_out, int out_size, void* d_ws, size_t ws_size,
                              hipStream_t stream)
{
    const float* x  = (const float*)d_in[0];
    const float* y  = (const float*)d_in[1];
    const float* Wq = (const float*)d_in[2];
    const float* Wk = (const float*)d_in[3];
    const float* Wv = (const float*)d_in[4];
    const float* Wp = (const float*)d_in[5];
    const float* bp = (const float*)d_in[6];
    const float* gx = (const float*)d_in[7];
    const float* bx = (const float*)d_in[8];
    const float* gy = (const float*)d_in[9];
    const float* by = (const float*)d_in[10];
    const float* gz = (const float*)d_in[11];
    const float* bz = (const float*)d_in[12];

    constexpr size_t WB = 576 * 576 * 2;           // one bf16 weight matrix (bytes)
    constexpr size_t XB = 16384ull * 576 * 2;      // one bf16 activation (bytes)
    constexpr size_t TOK = (size_t)2048 * 576;     // elements per batch of activation
    constexpr size_t SB  = (size_t)2048 * 2048;    // elements per batch of S

    char* w = (char*)d_ws;
    unsigned short* wq = (unsigned short*)(w);          // wq,wk,wv,wp contiguous
    unsigned short* wp = (unsigned short*)(w + 3 * WB);
    unsigned short* xn = (unsigned short*)(w + 4 * WB);
    unsigned short* yn = (unsigned short*)(w + 4 * WB + XB);
    unsigned short* q  = (unsigned short*)(w + 4 * WB + 2 * XB);
    unsigned short* k  = (unsigned short*)(w + 4 * WB + 3 * XB);
    unsigned short* vt = (unsigned short*)(w + 4 * WB + 4 * XB);  // [8][576][2048]
    unsigned short* S  = (unsigned short*)(w + 4 * WB + 5 * XB);  // [8][2048][2048], 67 MB
    unsigned short* attno = yn;       // yn dead after q projection
    unsigned short* T = q;            // q dead after attention; bf16 T

    cvt4w<<<dim3(324, 4), 256, 0, stream>>>(Wq, Wk, Wv, Wp, wq);

    ln_pair<<<dim3(4096, 2), 256, 0, stream>>>(x, gx, bx, xn, y, gy, by, yn);

    const float SCALE = 0.041666666666666664f;  // 576^-0.5 = 1/24, folded into q
    // q/k/v projections: 3 x 128 m-tiles x 9 n-tiles = 3456 blocks
    qkv_proj<<<3456, 256, 0, stream>>>(xn, yn, wq, q, vt, SCALE);

    // S_b = sigmoid(q_b k_b^T)  [2048x2048] x 8: 8 x 16 x 16 = 2048 blocks
    gemm_nt<128, 128, 2, 2, 1><<<2048, 256, 0, stream>>>(
        q, k, S, nullptr, nullptr, 2048, 576, 16, 16, 1.0f, TOK, TOK, SB);
    // O_b = S_b v_b (NT vs Vt)  [2048x576] x 8: 8 x 16 x 9 = 1152 blocks
    gemm_nt<128, 64, 2, 2, 0><<<1152, 256, 0, stream>>>(
        S, vt, attno, nullptr, nullptr, 576, 2048, 16, 9, 1.0f, SB, TOK, TOK);

    // T = attno Wp^T + bp + xn (bf16): 128 x 9 = 1152 blocks
    gemm_nt<128, 64, 2, 2, 2><<<1152, 256, 0, stream>>>(
        attno, wp, T, xn, bp, 576, 576, 128, 9, 1.0f, 0, 0, 0);
    // out = LN(T)
    ln_final<<<4096, 256, 0, stream>>>(T, gz, bz, (float*)d_out);
}

// Round 8
// 321.267 us; speedup vs baseline: 1.3196x; 1.0125x over previous
//
#include <hip/hip_runtime.h>

typedef __bf16 bfrag __attribute__((ext_vector_type(8)));
typedef float f32x4 __attribute__((ext_vector_type(4)));

__device__ __forceinline__ unsigned short f2bf(float f) {
    unsigned int u = __float_as_uint(f);
    unsigned int r = (u + 0x7fffu + ((u >> 16) & 1u)) >> 16;
    return (unsigned short)r;
}
__device__ __forceinline__ float bf2f(unsigned short h) {
    return __uint_as_float(((unsigned int)h) << 16);
}

__device__ __forceinline__ void gll16(const unsigned short* g, unsigned short* l) {
    __builtin_amdgcn_global_load_lds(
        (const __attribute__((address_space(1))) unsigned int*)g,
        (__attribute__((address_space(3))) unsigned int*)l, 16, 0, 0);
}

// fast sigmoid: v_exp + v_rcp (raw), plenty for bf16 output
__device__ __forceinline__ float fsigmoid(float v) {
    return __builtin_amdgcn_rcpf(1.0f + __expf(-v));
}

// Swizzled frag address (shorts): logical (row r, 16B-k-chunk kc) of a BK=64 tile.
// Wave-chunk = 8 rows x 8 chunks (1KB); slot = (r&7)*8 + (kc ^ (r&7)). Conflict-free.
__device__ __forceinline__ int swz(int r, int kc) {
    return (r >> 3) * 512 + (((r & 7) * 8 + (kc ^ (r & 7))) * 8);
}

// ---------------- generic NT GEMM, BK=64, swizzled LDS, XCD-aware 1D grid ----------------
// C = A[M,K] * B^T, B is [N,K]. 1D grid; xcd=id&7 owns whole (z,m)-stripes -> A-stripe
// fetched once per XCD L2. All dims/tiling compile-time; staging uses bumped pointers.
// EPI: 0 = store bf16 (v*scale); 1 = sigmoid -> bf16; 2 = +bias[col]+residual -> bf16
template<int BM, int BN, int WR, int WC, int EPI, int TM, int TN, int N, int K>
__global__ __launch_bounds__(256) void gemm_nt(
    const unsigned short* __restrict__ A, const unsigned short* __restrict__ B,
    unsigned short* __restrict__ Cb,
    const unsigned short* __restrict__ R, const float* __restrict__ bias,
    float scale, size_t sAz, size_t sBz, size_t sCz)
{
    constexpr int BK = 64;
    constexpr int WTM = BM / (WR * 16);
    constexpr int WTN = BN / (WC * 16);
    constexpr int NA = BM / 32, NB = BN / 32;
    __shared__ unsigned short sA[BM * BK];
    __shared__ unsigned short sB[BN * BK];

    // XCD-aware decode (all compile-time divisors)
    const int id  = blockIdx.x;
    const int j   = id >> 3;
    const int s   = (id & 7) + 8 * (j / TN);
    const int bn0 = (j % TN) * BN;
    const int bm0 = (s % TM) * BM;
    const int z   = s / TM;

    A += (size_t)z * sAz;
    B += (size_t)z * sBz;

    const int tid  = threadIdx.x;
    const int w    = tid >> 6;
    const int lane = tid & 63;
    const int wm = w / WC;
    const int wn = w % WC;
    const int rl  = lane >> 3;            // row within wave-chunk (0..7)
    const int kcs = (lane & 7) ^ rl;      // swizzled source k-chunk
    const int mrow = lane & 15;
    const int kgrp = lane >> 4;

    // per-thread staging source pointers, bumped by BK per step
    const unsigned short* pA[NA];
    const unsigned short* pB[NB];
    #pragma unroll
    for (int i = 0; i < NA; ++i) {
        int wc = w * NA + i;
        pA[i] = A + (size_t)(bm0 + wc * 8 + rl) * K + kcs * 8;
    }
    #pragma unroll
    for (int i = 0; i < NB; ++i) {
        int wc = w * NB + i;
        pB[i] = B + (size_t)(bn0 + wc * 8 + rl) * K + kcs * 8;
    }

    f32x4 acc[WTM][WTN] = {};

    for (int k0 = 0; k0 < K; k0 += BK) {
        #pragma unroll
        for (int i = 0; i < NA; ++i) {
            gll16(pA[i], &sA[(w * NA + i) * 512 + lane * 8]);
            pA[i] += BK;
        }
        #pragma unroll
        for (int i = 0; i < NB; ++i) {
            gll16(pB[i], &sB[(w * NB + i) * 512 + lane * 8]);
            pB[i] += BK;
        }
        __syncthreads();

        #pragma unroll
        for (int kh = 0; kh < 2; ++kh) {
            bfrag af[WTM], bfr[WTN];
            #pragma unroll
            for (int mt = 0; mt < WTM; ++mt)
                af[mt] = *(const bfrag*)&sA[swz(wm * WTM * 16 + mt * 16 + mrow, kh * 4 + kgrp)];
            #pragma unroll
            for (int nt = 0; nt < WTN; ++nt)
                bfr[nt] = *(const bfrag*)&sB[swz(wn * WTN * 16 + nt * 16 + mrow, kh * 4 + kgrp)];
            #pragma unroll
            for (int mt = 0; mt < WTM; ++mt)
                #pragma unroll
                for (int nt = 0; nt < WTN; ++nt)
                    acc[mt][nt] = __builtin_amdgcn_mfma_f32_16x16x32_bf16(af[mt], bfr[nt], acc[mt][nt], 0, 0, 0);
        }
        __syncthreads();
    }

    #pragma unroll
    for (int mt = 0; mt < WTM; ++mt) {
        #pragma unroll
        for (int nt = 0; nt < WTN; ++nt) {
            int grow0 = bm0 + wm * WTM * 16 + mt * 16 + kgrp * 4;
            int gcol  = bn0 + wn * WTN * 16 + nt * 16 + mrow;
            #pragma unroll
            for (int r = 0; r < 4; ++r) {
                float v = acc[mt][nt][r];
                size_t off = (size_t)z * sCz + (size_t)(grow0 + r) * N + gcol;
                if (EPI == 0) {
                    Cb[off] = f2bf(v * scale);
                } else if (EPI == 1) {
                    Cb[off] = f2bf(fsigmoid(v));
                } else {
                    Cb[off] = f2bf(v + bias[gcol] + bf2f(R[off]));
                }
            }
        }
    }
}

// ---------------- fused QKV projection (BK=64, swizzled, XCD-aware) ----------------
// stripe z: 0: q = (yn Wq^T)*SCALE; 1: k = xn Wk^T; 2: vt-pack of xn Wv^T
__global__ __launch_bounds__(256) void qkv_proj(
    const unsigned short* __restrict__ xn, const unsigned short* __restrict__ yn,
    const unsigned short* __restrict__ W,   // [3][576][576] bf16
    unsigned short* __restrict__ qk,        // q then k, [2][16384][576]
    unsigned short* __restrict__ vt,        // [8][576][2048]
    float scale)
{
    constexpr int BM = 128, BN = 64, BK = 64;
    constexpr int WTM = 4, WTN = 2;         // WR=2, WC=2
    constexpr int NA = 4, NB = 2;
    __shared__ unsigned short sA[BM * BK];
    __shared__ unsigned short sB[BN * BK];

    const int id  = blockIdx.x;
    const int j   = id >> 3;
    const int s   = (id & 7) + 8 * (j / 9);   // TN = 9
    const int bn0 = (j % 9) * BN;
    const int bm0 = (s % 128) * BM;           // TM = 128
    const int z   = s / 128;

    const unsigned short* A = (z == 0) ? yn : xn;
    const unsigned short* B = W + (size_t)z * 576 * 576;
    const float sc = (z == 0) ? scale : 1.0f;

    const int tid  = threadIdx.x;
    const int w    = tid >> 6;
    const int lane = tid & 63;
    const int wm = w >> 1;
    const int wn = w & 1;
    const int rl  = lane >> 3;
    const int kcs = (lane & 7) ^ rl;
    const int mrow = lane & 15;
    const int kgrp = lane >> 4;

    const unsigned short* pA[NA];
    const unsigned short* pB[NB];
    #pragma unroll
    for (int i = 0; i < NA; ++i) {
        int wc = w * NA + i;
        pA[i] = A + (size_t)(bm0 + wc * 8 + rl) * 576 + kcs * 8;
    }
    #pragma unroll
    for (int i = 0; i < NB; ++i) {
        int wc = w * NB + i;
        pB[i] = B + (size_t)(bn0 + wc * 8 + rl) * 576 + kcs * 8;
    }

    f32x4 acc[WTM][WTN] = {};

    for (int k0 = 0; k0 < 576; k0 += BK) {
        #pragma unroll
        for (int i = 0; i < NA; ++i) {
            gll16(pA[i], &sA[(w * NA + i) * 512 + lane * 8]);
            pA[i] += BK;
        }
        #pragma unroll
        for (int i = 0; i < NB; ++i) {
            gll16(pB[i], &sB[(w * NB + i) * 512 + lane * 8]);
            pB[i] += BK;
        }
        __syncthreads();

        #pragma unroll
        for (int kh = 0; kh < 2; ++kh) {
            bfrag af[WTM], bfr[WTN];
            #pragma unroll
            for (int mt = 0; mt < WTM; ++mt)
                af[mt] = *(const bfrag*)&sA[swz(wm * WTM * 16 + mt * 16 + mrow, kh * 4 + kgrp)];
            #pragma unroll
            for (int nt = 0; nt < WTN; ++nt)
                bfr[nt] = *(const bfrag*)&sB[swz(wn * WTN * 16 + nt * 16 + mrow, kh * 4 + kgrp)];
            #pragma unroll
            for (int mt = 0; mt < WTM; ++mt)
                #pragma unroll
                for (int nt = 0; nt < WTN; ++nt)
                    acc[mt][nt] = __builtin_amdgcn_mfma_f32_16x16x32_bf16(af[mt], bfr[nt], acc[mt][nt], 0, 0, 0);
        }
        __syncthreads();
    }

    #pragma unroll
    for (int mt = 0; mt < WTM; ++mt) {
        #pragma unroll
        for (int nt = 0; nt < WTN; ++nt) {
            int grow0 = bm0 + wm * WTM * 16 + mt * 16 + kgrp * 4;
            int gcol  = bn0 + wn * WTN * 16 + nt * 16 + mrow;
            if (z == 2) {
                ushort4 o;
                o.x = f2bf(acc[mt][nt][0]);
                o.y = f2bf(acc[mt][nt][1]);
                o.z = f2bf(acc[mt][nt][2]);
                o.w = f2bf(acc[mt][nt][3]);
                size_t dst = (((size_t)(grow0 >> 11) * 576 + gcol) << 11) + (grow0 & 2047);
                *(ushort4*)(vt + dst) = o;
            } else {
                unsigned short* C = qk + (size_t)z * 16384 * 576;
                #pragma unroll
                for (int r = 0; r < 4; ++r)
                    C[(size_t)(grow0 + r) * 576 + gcol] = f2bf(acc[mt][nt][r] * sc);
            }
        }
    }
}

// ---------------- LayerNorms ----------------
__global__ __launch_bounds__(256) void ln_pair(
    const float* __restrict__ x, const float* __restrict__ gx, const float* __restrict__ bx,
    unsigned short* __restrict__ xn,
    const float* __restrict__ y, const float* __restrict__ gy, const float* __restrict__ by,
    unsigned short* __restrict__ yn)
{
    const float* src = blockIdx.y ? y : x;
    const float* g   = blockIdx.y ? gy : gx;
    const float* bb  = blockIdx.y ? by : bx;
    unsigned short* o = blockIdx.y ? yn : xn;

    const int row  = blockIdx.x * 4 + (threadIdx.x >> 6);
    const int lane = threadIdx.x & 63;
    const float* xr = src + (size_t)row * 576;
    float vals[9];
    float s = 0.f, ss = 0.f;
    #pragma unroll
    for (int i = 0; i < 9; ++i) {
        float v = xr[lane + i * 64];
        vals[i] = v; s += v; ss += v * v;
    }
    #pragma unroll
    for (int off = 32; off > 0; off >>= 1) {
        s  += __shfl_xor(s, off, 64);
        ss += __shfl_xor(ss, off, 64);
    }
    float mean = s * (1.0f / 576.0f);
    float var  = ss * (1.0f / 576.0f) - mean * mean;
    float rstd = rsqrtf(var + 1e-5f);
    #pragma unroll
    for (int i = 0; i < 9; ++i) {
        int c = lane + i * 64;
        o[(size_t)row * 576 + c] = f2bf((vals[i] - mean) * rstd * g[c] + bb[c]);
    }
}

// Final LN: bf16 in -> fp32 out
__global__ __launch_bounds__(256) void ln_final(
    const unsigned short* __restrict__ x, const float* __restrict__ g,
    const float* __restrict__ bb, float* __restrict__ outp)
{
    const int row  = blockIdx.x * 4 + (threadIdx.x >> 6);
    const int lane = threadIdx.x & 63;
    const unsigned short* xr = x + (size_t)row * 576;
    float vals[9];
    float s = 0.f, ss = 0.f;
    #pragma unroll
    for (int i = 0; i < 9; ++i) {
        float v = bf2f(xr[lane + i * 64]);
        vals[i] = v; s += v; ss += v * v;
    }
    #pragma unroll
    for (int off = 32; off > 0; off >>= 1) {
        s  += __shfl_xor(s, off, 64);
        ss += __shfl_xor(ss, off, 64);
    }
    float mean = s * (1.0f / 576.0f);
    float var  = ss * (1.0f / 576.0f) - mean * mean;
    float rstd = rsqrtf(var + 1e-5f);
    #pragma unroll
    for (int i = 0; i < 9; ++i) {
        int c = lane + i * 64;
        outp[(size_t)row * 576 + c] = (vals[i] - mean) * rstd * g[c] + bb[c];
    }
}

__global__ __launch_bounds__(256) void cvt4w(
    const float* __restrict__ s0, const float* __restrict__ s1,
    const float* __restrict__ s2, const float* __restrict__ s3,
    unsigned short* __restrict__ dst)
{
    const float* srcs[4] = {s0, s1, s2, s3};
    const float* src = srcs[blockIdx.y];
    unsigned short* d = dst + (size_t)blockIdx.y * 576 * 576;
    int i = (blockIdx.x * 256 + threadIdx.x) * 4;
    float4 f = *(const float4*)(src + i);
    ushort4 o;
    o.x = f2bf(f.x); o.y = f2bf(f.y); o.z = f2bf(f.z); o.w = f2bf(f.w);
    *(ushort4*)(d + i) = o;
}

extern "C" void kernel_launch(void* const* d_in, const int* in_sizes, int n_in,
                              void* d_out, int out_size, void* d_ws, size_t ws_size,
                              hipStream_t stream)
{
    const float* x  = (const float*)d_in[0];
    const float* y  = (const float*)d_in[1];
    const float* Wq = (const float*)d_in[2];
    const float* Wk = (const float*)d_in[3];
    const float* Wv = (const float*)d_in[4];
    const float* Wp = (const float*)d_in[5];
    const float* bp = (const float*)d_in[6];
    const float* gx = (const float*)d_in[7];
    const float* bx = (const float*)d_in[8];
    const float* gy = (const float*)d_in[9];
    const float* by = (const float*)d_in[10];
    const float* gz = (const float*)d_in[11];
    const float* bz = (const float*)d_in[12];

    constexpr size_t WB = 576 * 576 * 2;           // one bf16 weight matrix (bytes)
    constexpr size_t XB = 16384ull * 576 * 2;      // one bf16 activation (bytes)
    constexpr size_t TOK = (size_t)2048 * 576;     // elements per batch of activation
    constexpr size_t SB  = (size_t)2048 * 2048;    // elements per batch of S

    char* w = (char*)d_ws;
    unsigned short* wq = (unsigned short*)(w);          // wq,wk,wv,wp contiguous
    unsigned short* wp = (unsigned short*)(w + 3 * WB);
    unsigned short* xn = (unsigned short*)(w + 4 * WB);
    unsigned short* yn = (unsigned short*)(w + 4 * WB + XB);
    unsigned short* q  = (unsigned short*)(w + 4 * WB + 2 * XB);
    unsigned short* k  = (unsigned short*)(w + 4 * WB + 3 * XB);
    unsigned short* vt = (unsigned short*)(w + 4 * WB + 4 * XB);  // [8][576][2048]
    unsigned short* S  = (unsigned short*)(w + 4 * WB + 5 * XB);  // [8][2048][2048], 67 MB
    unsigned short* attno = yn;       // yn dead after q projection
    unsigned short* T = q;            // q dead after attention; bf16 T

    cvt4w<<<dim3(324, 4), 256, 0, stream>>>(Wq, Wk, Wv, Wp, wq);

    ln_pair<<<dim3(4096, 2), 256, 0, stream>>>(x, gx, bx, xn, y, gy, by, yn);

    const float SCALE = 0.041666666666666664f;  // 576^-0.5 = 1/24, folded into q
    // q/k/v projections: 3 x 128 m-tiles x 9 n-tiles = 3456 blocks
    qkv_proj<<<3456, 256, 0, stream>>>(xn, yn, wq, q, vt, SCALE);

    // S_b = sigmoid(q_b k_b^T)  [2048x2048] x 8: 2048 blocks
    gemm_nt<128, 128, 2, 2, 1, 16, 16, 2048, 576><<<2048, 256, 0, stream>>>(
        q, k, S, nullptr, nullptr, 1.0f, TOK, TOK, SB);
    // O_b = S_b v_b (NT vs Vt)  [2048x576] x 8: 1152 blocks
    gemm_nt<128, 64, 2, 2, 0, 16, 9, 576, 2048><<<1152, 256, 0, stream>>>(
        S, vt, attno, nullptr, nullptr, 1.0f, SB, TOK, TOK);

    // T = attno Wp^T + bp + xn (bf16): 1152 blocks
    gemm_nt<128, 64, 2, 2, 2, 128, 9, 576, 576><<<1152, 256, 0, stream>>>(
        attno, wp, T, xn, bp, 1.0f, 0, 0, 0);
    // out = LN(T)
    ln_final<<<4096, 256, 0, stream>>>(T, gz, bz, (float*)d_out);
}